// Round 6
// baseline (5929.190 us; speedup 1.0000x reference)
//
#include <hip/hip_runtime.h>
#include <math.h>

// Problem constants: B=512, T=2048, D=10, H=20
#define BB 512
#define TT 2048
#define DD 10
#define HH 20
#define BH (BB*HH)          // 10240 elements per timestep

// ws layout (word indices from base)
#define WS_AMAX     0
#define WS_PROD_XWI 4
#define WS_INV_SX   5
#define WS_S_H0     6
#define WS_INV_SH0  7
#define WS_S_WH     8
#define WS_BQ       16
#define WS_WIP      40
#define WS_WHP      104
#define WS_XW_OFF   4096     // byte offset of xW / out_t buffer: [T][B][H] floats (84 MB)

// LDS-only barrier: never drains vmcnt (prefetch loads / output stores stay in flight)
#define BAR() asm volatile("s_waitcnt lgkmcnt(0)\n\ts_barrier" ::: "memory")

__device__ __forceinline__ int dot4(int a, int b, int c) {
    return __builtin_amdgcn_sdot4(a, b, c, false);
}

// scale = exp2(ceil(log2(max(m,1e-10))))/128 via exponent bits (exact, branchless)
__device__ __forceinline__ void p2s(float m, float* s, float* is) {
    m = fmaxf(m, 1e-10f);
    unsigned u = __float_as_uint(m);
    int k = (int)(u >> 23) - 127 + ((u & 0x7fffffu) ? 1 : 0);  // ceil(log2(m))
    *s  = __uint_as_float((unsigned)(k + 120) << 23);           // 2^(k-7)
    *is = __uint_as_float((unsigned)(134 - k) << 23);           // 2^(7-k)
}

__device__ __forceinline__ float fmed3(float a, float b, float c) {
    return __builtin_amdgcn_fmed3f(a, b, c);
}

__device__ __forceinline__ int qlevel(float v, float inv) {
    return (int)fmed3(rintf(v * inv), -128.f, 127.f);
}

__device__ __forceinline__ int pack4(int a, int b, int c, int d) {
    return (a & 255) | ((b & 255) << 8) | ((c & 255) << 16) | ((d & 255) << 24);
}

// monotone float<->uint encoding: order-preserving for all finite floats
__device__ __forceinline__ unsigned fenc(float x) {
    unsigned u = __float_as_uint(x);
    return u ^ (unsigned)(((int)u >> 31) | 0x80000000);
}
__device__ __forceinline__ float fdec(unsigned e) {
    unsigned mask = (~(unsigned)((int)e >> 31)) | 0x80000000u;
    return __uint_as_float(e ^ mask);
}

__device__ __forceinline__ unsigned umx(unsigned a, unsigned b) { return a > b ? a : b; }

// wave64 umax via DPP (VALU only, no LDS): lane63 holds the full max
__device__ __forceinline__ unsigned wave_umax(unsigned m) {
    unsigned t;
    t = (unsigned)__builtin_amdgcn_update_dpp(0, (int)m, 0x111, 0xf, 0xf, true); m = umx(m, t); // shr1
    t = (unsigned)__builtin_amdgcn_update_dpp(0, (int)m, 0x112, 0xf, 0xf, true); m = umx(m, t); // shr2
    t = (unsigned)__builtin_amdgcn_update_dpp(0, (int)m, 0x114, 0xf, 0xf, true); m = umx(m, t); // shr4
    t = (unsigned)__builtin_amdgcn_update_dpp(0, (int)m, 0x118, 0xf, 0xf, true); m = umx(m, t); // shr8
    t = (unsigned)__builtin_amdgcn_update_dpp(0, (int)m, 0x142, 0xa, 0xf, true); m = umx(m, t); // bcast15
    t = (unsigned)__builtin_amdgcn_update_dpp(0, (int)m, 0x143, 0xc, 0xf, true); m = umx(m, t); // bcast31
    return m;
}

// umax over each 16-lane row (cyclic): every lane gets the row max
__device__ __forceinline__ unsigned row_umax(unsigned m) {
    unsigned t;
    t = (unsigned)__builtin_amdgcn_update_dpp(0, (int)m, 0x121, 0xf, 0xf, true); m = umx(m, t); // ror1
    t = (unsigned)__builtin_amdgcn_update_dpp(0, (int)m, 0x122, 0xf, 0xf, true); m = umx(m, t); // ror2
    t = (unsigned)__builtin_amdgcn_update_dpp(0, (int)m, 0x124, 0xf, 0xf, true); m = umx(m, t); // ror4
    t = (unsigned)__builtin_amdgcn_update_dpp(0, (int)m, 0x128, 0xf, 0xf, true); m = umx(m, t); // ror8
    return m;
}

// ---------------- kernel 1: maxabs(x) grid reduction -------------------------
__global__ void k_amax(const float* __restrict__ x, int n4, unsigned* amax) {
    int g = blockIdx.x * blockDim.x + threadIdx.x;
    int stride = gridDim.x * blockDim.x;
    const float4* xv = (const float4*)x;
    float m = 0.f;
    for (int i = g; i < n4; i += stride) {
        float4 v = xv[i];
        m = fmaxf(m, fmaxf(fmaxf(fabsf(v.x), fabsf(v.y)), fmaxf(fabsf(v.z), fabsf(v.w))));
    }
#pragma unroll
    for (int off = 32; off; off >>= 1) m = fmaxf(m, __shfl_xor(m, off, 64));
    if ((threadIdx.x & 63) == 0) atomicMax(amax, __float_as_uint(m));
}

// ---------------- kernel 2: scales + weight quant/pack -----------------------
__device__ float bmaxabs(const float* p, int n, float* red, int tid) {
    float m = 0.f;
    for (int i = tid; i < n; i += 256) m = fmaxf(m, fabsf(p[i]));
    red[tid] = m; __syncthreads();
    for (int s = 128; s; s >>= 1) {
        if (tid < s) red[tid] = fmaxf(red[tid], red[tid + s]);
        __syncthreads();
    }
    m = red[0]; __syncthreads();
    return m;
}

__global__ void k_prep(const float* __restrict__ Wi, const float* __restrict__ Wh,
                       const float* __restrict__ bias, const float* __restrict__ h0,
                       float* wsf, int* wsi) {
    __shared__ float red[256];
    __shared__ float hdr[4];
    int tid = threadIdx.x;
    float mwi = bmaxabs(Wi, HH * DD, red, tid);
    float mwh = bmaxabs(Wh, HH * HH, red, tid);
    float mb  = bmaxabs(bias, HH, red, tid);
    float mh0 = bmaxabs(h0, BH, red, tid);
    if (tid == 0) {
        float mx = __uint_as_float(((unsigned*)wsf)[WS_AMAX]);
        float sx, isx, swi, iswi, swh, iswh, sb, isb, sh0, ish0;
        p2s(mx,  &sx,  &isx);
        p2s(mwi, &swi, &iswi);
        p2s(mwh, &swh, &iswh);
        p2s(mb,  &sb,  &isb);
        p2s(mh0, &sh0, &ish0);
        wsf[WS_PROD_XWI] = sx * swi;
        wsf[WS_INV_SX]   = isx;
        wsf[WS_S_H0]     = sh0;
        wsf[WS_INV_SH0]  = ish0;
        wsf[WS_S_WH]     = swh;
        hdr[0] = iswi; hdr[1] = iswh; hdr[2] = sb; hdr[3] = isb;
    }
    __syncthreads();
    if (tid < HH) {
        float iswi = hdr[0], iswh = hdr[1], sb = hdr[2], isb = hdr[3];
        int lv[20];
#pragma unroll
        for (int d = 0; d < DD; ++d) lv[d] = qlevel(Wi[tid * DD + d], iswi);
        lv[10] = 0; lv[11] = 0;
#pragma unroll
        for (int k = 0; k < 3; ++k)
            wsi[WS_WIP + tid * 3 + k] = pack4(lv[4*k], lv[4*k+1], lv[4*k+2], lv[4*k+3]);
#pragma unroll
        for (int k = 0; k < HH; ++k) lv[k] = qlevel(Wh[tid * HH + k], iswh);
#pragma unroll
        for (int k = 0; k < 5; ++k)
            wsi[WS_WHP + tid * 5 + k] = pack4(lv[4*k], lv[4*k+1], lv[4*k+2], lv[4*k+3]);
        wsf[WS_BQ + tid] = (float)qlevel(bias[tid], isb) * sb;
    }
}

// ---------------- kernel 3: xW[t][b][j] = quant(x)·Wi_q + bq -----------------
__global__ __launch_bounds__(256) void k_xw(const float* __restrict__ x,
                                            const float* __restrict__ wsf,
                                            const int* __restrict__ wsi,
                                            float* __restrict__ xw) {
    int g = blockIdx.x * 256 + threadIdx.x;
    int b = g & (BB - 1);
    int t = g >> 9;
    float isx  = wsf[WS_INV_SX];
    float prod = wsf[WS_PROD_XWI];
    const float2* xp = (const float2*)(x + ((size_t)b * TT + t) * DD);
    float xv[10];
#pragma unroll
    for (int k = 0; k < 5; ++k) { float2 v = xp[k]; xv[2*k] = v.x; xv[2*k+1] = v.y; }
    int lv[12];
#pragma unroll
    for (int d = 0; d < DD; ++d) lv[d] = qlevel(xv[d], isx);
    lv[10] = 0; lv[11] = 0;
    int xpk[3];
#pragma unroll
    for (int k = 0; k < 3; ++k) xpk[k] = pack4(lv[4*k], lv[4*k+1], lv[4*k+2], lv[4*k+3]);
    float res[20];
#pragma unroll
    for (int j = 0; j < HH; ++j) {
        int ai = 0;
#pragma unroll
        for (int k = 0; k < 3; ++k) ai = dot4(xpk[k], wsi[WS_WIP + j * 3 + k], ai);
        res[j] = (float)ai * prod + wsf[WS_BQ + j];
    }
    float4* op = (float4*)(xw + (size_t)t * BH + b * HH);
#pragma unroll
    for (int k = 0; k < 5; ++k)
        op[k] = make_float4(res[4*k], res[4*k+1], res[4*k+2], res[4*k+3]);
}

// ---------------- kernel 4: serial recurrence, 1 workgroup -------------------
// 1024 threads (16 waves = 4/SIMD for latency hiding), thread = (b, jhalf)
// with b = tid&511, jhalf = tid>>9 —> jhalf is WAVE-UNIFORM, so each thread's
// 10 Wh rows (50 dwords) load via readfirstlane-scalarized addresses into
// 50 SGPRs (s_load). v_dot4 takes the SGPR operand directly: zero per-step
// weight-reload cost and VGPR pressure drops to ~70 (R4 spilled whp from a
// 56-VGPR allocation; R5 proved the SGPR path but died at 2 waves/SIMD).
// amdgpu_waves_per_eu(4,4): tell the allocator not to target occupancy >4
// waves/EU (only one block ever runs). h-halves of a b-row live in different
// waves -> exchange via LDS hx[] with a 3rd LDS-only barrier.
__global__ __launch_bounds__(1024)
__attribute__((amdgpu_waves_per_eu(4, 4)))
void k_rnn(const float* __restrict__ h0,
           const float* __restrict__ wsf,
           const int* __restrict__ wsi,
           float* __restrict__ xw) {
    __shared__ uint2 wred[16];
    __shared__ float bc[4];
    __shared__ int2 lut[256];
    __shared__ int4 hx[1024];
    const int tid = threadIdx.x;
    const int b = tid & 511;
    const int hf = tid >> 9;                 // wave-uniform
    const int jb = hf * 10;
    const int jbu = __builtin_amdgcn_readfirstlane(jb);   // force scalar
    const float s_wh = wsf[WS_S_WH];
    float sprod = wsf[WS_S_H0] * s_wh;

    int whp[50];   // 10 packed Wh rows -> SGPRs (scalar base address)
    const int* wrow = wsi + WS_WHP + jbu * 5;
#pragma unroll
    for (int i = 0; i < 50; ++i) whp[i] = wrow[i];

    int hd[5];
    {   // full h0 row -> levels -> 5 packed dwords (both half-threads redundant)
        float ish0 = wsf[WS_INV_SH0];
        const float4* hp = (const float4*)(h0 + b * HH);
        int lv[20];
#pragma unroll
        for (int k = 0; k < 5; ++k) {
            float4 v = hp[k];
            lv[4*k]   = qlevel(v.x, ish0);
            lv[4*k+1] = qlevel(v.y, ish0);
            lv[4*k+2] = qlevel(v.z, ish0);
            lv[4*k+3] = qlevel(v.w, ish0);
        }
#pragma unroll
        for (int k = 0; k < 5; ++k)
            hd[k] = pack4(lv[4*k], lv[4*k+1], lv[4*k+2], lv[4*k+3]);
    }

    float xw0[10], xw1[10];
    {   // preload own half of row t=0
        const float2* p = (const float2*)(xw + b * HH + jb);
#pragma unroll
        for (int k = 0; k < 5; ++k) { float2 v = p[k]; xw0[2*k] = v.x; xw0[2*k+1] = v.y; }
    }
    const float2* pf = (const float2*)(xw + (size_t)BH + b * HH + jb);  // row t+1
    float2*       po = (float2*)(xw + b * HH + jb);                      // row t

    auto step = [&](int t, float (&xa)[10], float (&xb)[10]) {
        if (t + 1 < TT) {   // prefetch; stays in flight across LDS-only barriers
#pragma unroll
            for (int k = 0; k < 5; ++k) { float2 v = pf[k]; xb[2*k] = v.x; xb[2*k+1] = v.y; }
        }
        float acc[10];
#pragma unroll
        for (int jj = 0; jj < 10; ++jj) {
            int ai = 0;
#pragma unroll
            for (int k = 0; k < 5; ++k) ai = dot4(hd[k], whp[jj * 5 + k], ai);
            acc[jj] = fmaf((float)ai, sprod, xa[jj]);   // exact: |ai| < 2^24, pow2 scale
        }
        float mx = acc[0], mn = acc[0];
#pragma unroll
        for (int jj = 1; jj < 10; ++jj) { mx = fmaxf(mx, acc[jj]); mn = fminf(mn, acc[jj]); }
        unsigned ea = wave_umax(fenc(mx));    // max(acc)
        unsigned eb = wave_umax(fenc(-mn));   // max(-acc)
        if ((tid & 63) == 63) wred[tid >> 6] = make_uint2(ea, eb);
        BAR();   // B1
        float isa, sh;
        if (tid < 256) {   // waves 0-3: cross-wave reduce + scales + exact LUT
            uint2 wp = wred[tid & 15];
            float ma = fdec(row_umax(wp.x));
            float nm = fdec(row_umax(wp.y));
            float sa; p2s(fmaxf(ma, nm), &sa, &isa);
            float lp = fmed3(rintf(ma * isa), -128.f, 127.f);
            float ln = fmed3(rintf(-nm * isa), -128.f, 127.f);
            float mlvl = fmaxf(fabsf(lp), fabsf(ln));   // max |acc_q| (clip asym incl.)
            float mh = tanhf(mlvl * sa);                // max |h_new| (tanh monotone)
            float ish; p2s(mh, &sh, &ish);
            sprod = sh * s_wh;
            float tq = tanhf((float)(tid - 128) * sa);  // exact LUT entry
            int lv = (int)fmed3(rintf(tq * ish), -128.f, 127.f);
            lut[tid] = make_int2(lv, __float_as_int((float)lv * sh));
            if (tid == 0) { bc[0] = isa; bc[1] = sh; bc[2] = sprod; }
        }
        BAR();   // B2
        if (tid >= 256) { isa = bc[0]; sprod = bc[2]; }
        int ql[10];
#pragma unroll
        for (int k = 0; k < 5; ++k) {   // gather {level, out-bits}, store pair
            int qa = (int)fmed3(rintf(acc[2*k]   * isa), -128.f, 127.f);
            int qb = (int)fmed3(rintf(acc[2*k+1] * isa), -128.f, 127.f);
            int2 e0 = lut[qa + 128];
            int2 e1 = lut[qb + 128];
            ql[2*k]   = e0.x;
            ql[2*k+1] = e1.x;
            po[k] = make_float2(__int_as_float(e0.y), __int_as_float(e1.y));
        }
        {   // h-exchange between the two half-threads of b (different waves)
            int P0 = pack4(ql[0], ql[1], ql[2], ql[3]);
            int P1 = pack4(ql[4], ql[5], ql[6], ql[7]);
            int P2 = (ql[8] & 255) | ((ql[9] & 255) << 8);
            hx[tid] = make_int4(P0, P1, P2, 0);
            BAR();   // B3
            int4 q = hx[tid ^ 512];
            int X0 = hf ? q.x : P0, X1 = hf ? q.y : P1, X2 = hf ? q.z : P2;  // j 0-9
            int Y0 = hf ? P0 : q.x, Y1 = hf ? P1 : q.y, Y2 = hf ? P2 : q.z;  // j 10-19
            hd[0] = X0; hd[1] = X1;
            hd[2] = (X2 & 0xFFFF) | (Y0 << 16);
            hd[3] = (int)((unsigned)Y0 >> 16) | (Y1 << 16);
            hd[4] = (int)((unsigned)Y1 >> 16) | (Y2 << 16);
        }
        pf += BH / 2;
        po += BH / 2;
    };

    for (int t = 0; t < TT; t += 2) {   // ping-pong: no xa=xb copy
        step(t, xw0, xw1);
        step(t + 1, xw1, xw0);
    }
}

// ---------------- kernel 5: transpose [T][B][H] -> [B][T][H] -----------------
__global__ __launch_bounds__(256) void k_tr(const float* __restrict__ src, float* __restrict__ out) {
    __shared__ float tile[16 * 16 * HH];   // 20 KB
    int t0 = blockIdx.x * 16, b0 = blockIdx.y * 16;
    for (int i = threadIdx.x; i < 16 * 16 * HH; i += 256) {
        int r = i / (16 * HH), c = i % (16 * HH);
        tile[i] = src[(size_t)(t0 + r) * BH + b0 * HH + c];
    }
    __syncthreads();
    for (int i = threadIdx.x; i < 16 * 16 * HH; i += 256) {
        int bb = i / (16 * HH), rj = i % (16 * HH);
        int r = rj / HH, j = rj % HH;
        out[(size_t)(b0 + bb) * (TT * HH) + (t0 + r) * HH + j] = tile[r * (16 * HH) + bb * HH + j];
    }
}

extern "C" void kernel_launch(void* const* d_in, const int* in_sizes, int n_in,
                              void* d_out, int out_size, void* d_ws, size_t ws_size,
                              hipStream_t stream) {
    const float* x    = (const float*)d_in[0];
    const float* h0   = (const float*)d_in[1];
    const float* Wi   = (const float*)d_in[2];
    const float* Wh   = (const float*)d_in[3];
    const float* bias = (const float*)d_in[4];
    float* out = (float*)d_out;

    char* w = (char*)d_ws;
    float* wsf = (float*)w;
    int* wsi = (int*)w;
    unsigned* amax = (unsigned*)w;
    float* xw = (float*)(w + WS_XW_OFF);

    hipMemsetAsync(d_ws, 0, 64, stream);
    int n = in_sizes[0];
    k_amax<<<2048, 256, 0, stream>>>(x, n / 4, amax);
    k_prep<<<1, 256, 0, stream>>>(Wi, Wh, bias, h0, wsf, wsi);
    k_xw<<<(BB * TT) / 256, 256, 0, stream>>>(x, wsf, wsi, xw);
    k_rnn<<<1, 1024, 0, stream>>>(h0, wsf, wsi, xw);
    k_tr<<<dim3(TT / 16, BB / 16), 256, 0, stream>>>(xw, out);
}

// Round 7
// 5411.214 us; speedup vs baseline: 1.0957x; 1.0957x over previous
//
#include <hip/hip_runtime.h>
#include <math.h>

// Problem constants: B=512, T=2048, D=10, H=20
#define BB 512
#define TT 2048
#define DD 10
#define HH 20
#define BH (BB*HH)          // 10240 elements per timestep

// ws layout (word indices from base)
#define WS_AMAX     0
#define WS_PROD_XWI 4
#define WS_INV_SX   5
#define WS_S_H0     6
#define WS_INV_SH0  7
#define WS_S_WH     8
#define WS_BQ       16
#define WS_WIP      40
#define WS_WHP      104
#define WS_XW_OFF   4096     // byte offset of xW / out_t buffer: [T][B][H] floats (84 MB)

// LDS-only barrier: never drains vmcnt (prefetch loads / output stores stay in flight)
#define BAR() asm volatile("s_waitcnt lgkmcnt(0)\n\ts_barrier" ::: "memory")

__device__ __forceinline__ int dot4(int a, int b, int c) {
    return __builtin_amdgcn_sdot4(a, b, c, false);
}

// scale = exp2(ceil(log2(max(m,1e-10))))/128 via exponent bits (exact, branchless)
__device__ __forceinline__ void p2s(float m, float* s, float* is) {
    m = fmaxf(m, 1e-10f);
    unsigned u = __float_as_uint(m);
    int k = (int)(u >> 23) - 127 + ((u & 0x7fffffu) ? 1 : 0);  // ceil(log2(m))
    *s  = __uint_as_float((unsigned)(k + 120) << 23);           // 2^(k-7)
    *is = __uint_as_float((unsigned)(134 - k) << 23);           // 2^(7-k)
}

__device__ __forceinline__ float fmed3(float a, float b, float c) {
    return __builtin_amdgcn_fmed3f(a, b, c);
}

__device__ __forceinline__ int qlevel(float v, float inv) {
    return (int)fmed3(rintf(v * inv), -128.f, 127.f);
}

__device__ __forceinline__ int pack4(int a, int b, int c, int d) {
    return (a & 255) | ((b & 255) << 8) | ((c & 255) << 16) | ((d & 255) << 24);
}

// monotone float<->uint encoding: order-preserving for all finite floats
__device__ __forceinline__ unsigned fenc(float x) {
    unsigned u = __float_as_uint(x);
    return u ^ (unsigned)(((int)u >> 31) | 0x80000000);
}
__device__ __forceinline__ float fdec(unsigned e) {
    unsigned mask = (~(unsigned)((int)e >> 31)) | 0x80000000u;
    return __uint_as_float(e ^ mask);
}

__device__ __forceinline__ unsigned umx(unsigned a, unsigned b) { return a > b ? a : b; }

// wave64 umax via DPP (VALU only, no LDS): lane63 holds the full max
__device__ __forceinline__ unsigned wave_umax(unsigned m) {
    unsigned t;
    t = (unsigned)__builtin_amdgcn_update_dpp(0, (int)m, 0x111, 0xf, 0xf, true); m = umx(m, t); // shr1
    t = (unsigned)__builtin_amdgcn_update_dpp(0, (int)m, 0x112, 0xf, 0xf, true); m = umx(m, t); // shr2
    t = (unsigned)__builtin_amdgcn_update_dpp(0, (int)m, 0x114, 0xf, 0xf, true); m = umx(m, t); // shr4
    t = (unsigned)__builtin_amdgcn_update_dpp(0, (int)m, 0x118, 0xf, 0xf, true); m = umx(m, t); // shr8
    t = (unsigned)__builtin_amdgcn_update_dpp(0, (int)m, 0x142, 0xa, 0xf, true); m = umx(m, t); // bcast15
    t = (unsigned)__builtin_amdgcn_update_dpp(0, (int)m, 0x143, 0xc, 0xf, true); m = umx(m, t); // bcast31
    return m;
}

// umax over a period-8 lane pattern (cyclic within 16-lane rows)
__device__ __forceinline__ unsigned oct_umax(unsigned m) {
    unsigned t;
    t = (unsigned)__builtin_amdgcn_update_dpp(0, (int)m, 0x121, 0xf, 0xf, true); m = umx(m, t); // ror1
    t = (unsigned)__builtin_amdgcn_update_dpp(0, (int)m, 0x122, 0xf, 0xf, true); m = umx(m, t); // ror2
    t = (unsigned)__builtin_amdgcn_update_dpp(0, (int)m, 0x124, 0xf, 0xf, true); m = umx(m, t); // ror4
    return m;
}

// ---------------- kernel 1: maxabs(x) grid reduction -------------------------
__global__ void k_amax(const float* __restrict__ x, int n4, unsigned* amax) {
    int g = blockIdx.x * blockDim.x + threadIdx.x;
    int stride = gridDim.x * blockDim.x;
    const float4* xv = (const float4*)x;
    float m = 0.f;
    for (int i = g; i < n4; i += stride) {
        float4 v = xv[i];
        m = fmaxf(m, fmaxf(fmaxf(fabsf(v.x), fabsf(v.y)), fmaxf(fabsf(v.z), fabsf(v.w))));
    }
#pragma unroll
    for (int off = 32; off; off >>= 1) m = fmaxf(m, __shfl_xor(m, off, 64));
    if ((threadIdx.x & 63) == 0) atomicMax(amax, __float_as_uint(m));
}

// ---------------- kernel 2: scales + weight quant/pack -----------------------
__device__ float bmaxabs(const float* p, int n, float* red, int tid) {
    float m = 0.f;
    for (int i = tid; i < n; i += 256) m = fmaxf(m, fabsf(p[i]));
    red[tid] = m; __syncthreads();
    for (int s = 128; s; s >>= 1) {
        if (tid < s) red[tid] = fmaxf(red[tid], red[tid + s]);
        __syncthreads();
    }
    m = red[0]; __syncthreads();
    return m;
}

__global__ void k_prep(const float* __restrict__ Wi, const float* __restrict__ Wh,
                       const float* __restrict__ bias, const float* __restrict__ h0,
                       float* wsf, int* wsi) {
    __shared__ float red[256];
    __shared__ float hdr[4];
    int tid = threadIdx.x;
    float mwi = bmaxabs(Wi, HH * DD, red, tid);
    float mwh = bmaxabs(Wh, HH * HH, red, tid);
    float mb  = bmaxabs(bias, HH, red, tid);
    float mh0 = bmaxabs(h0, BH, red, tid);
    if (tid == 0) {
        float mx = __uint_as_float(((unsigned*)wsf)[WS_AMAX]);
        float sx, isx, swi, iswi, swh, iswh, sb, isb, sh0, ish0;
        p2s(mx,  &sx,  &isx);
        p2s(mwi, &swi, &iswi);
        p2s(mwh, &swh, &iswh);
        p2s(mb,  &sb,  &isb);
        p2s(mh0, &sh0, &ish0);
        wsf[WS_PROD_XWI] = sx * swi;
        wsf[WS_INV_SX]   = isx;
        wsf[WS_S_H0]     = sh0;
        wsf[WS_INV_SH0]  = ish0;
        wsf[WS_S_WH]     = swh;
        hdr[0] = iswi; hdr[1] = iswh; hdr[2] = sb; hdr[3] = isb;
    }
    __syncthreads();
    if (tid < HH) {
        float iswi = hdr[0], iswh = hdr[1], sb = hdr[2], isb = hdr[3];
        int lv[20];
#pragma unroll
        for (int d = 0; d < DD; ++d) lv[d] = qlevel(Wi[tid * DD + d], iswi);
        lv[10] = 0; lv[11] = 0;
#pragma unroll
        for (int k = 0; k < 3; ++k)
            wsi[WS_WIP + tid * 3 + k] = pack4(lv[4*k], lv[4*k+1], lv[4*k+2], lv[4*k+3]);
#pragma unroll
        for (int k = 0; k < HH; ++k) lv[k] = qlevel(Wh[tid * HH + k], iswh);
#pragma unroll
        for (int k = 0; k < 5; ++k)
            wsi[WS_WHP + tid * 5 + k] = pack4(lv[4*k], lv[4*k+1], lv[4*k+2], lv[4*k+3]);
        wsf[WS_BQ + tid] = (float)qlevel(bias[tid], isb) * sb;
    }
}

// ---------------- kernel 3: xW[t][b][j] = quant(x)·Wi_q + bq -----------------
__global__ __launch_bounds__(256) void k_xw(const float* __restrict__ x,
                                            const float* __restrict__ wsf,
                                            const int* __restrict__ wsi,
                                            float* __restrict__ xw) {
    int g = blockIdx.x * 256 + threadIdx.x;
    int b = g & (BB - 1);
    int t = g >> 9;
    float isx  = wsf[WS_INV_SX];
    float prod = wsf[WS_PROD_XWI];
    const float2* xp = (const float2*)(x + ((size_t)b * TT + t) * DD);
    float xv[10];
#pragma unroll
    for (int k = 0; k < 5; ++k) { float2 v = xp[k]; xv[2*k] = v.x; xv[2*k+1] = v.y; }
    int lv[12];
#pragma unroll
    for (int d = 0; d < DD; ++d) lv[d] = qlevel(xv[d], isx);
    lv[10] = 0; lv[11] = 0;
    int xpk[3];
#pragma unroll
    for (int k = 0; k < 3; ++k) xpk[k] = pack4(lv[4*k], lv[4*k+1], lv[4*k+2], lv[4*k+3]);
    float res[20];
#pragma unroll
    for (int j = 0; j < HH; ++j) {
        int ai = 0;
#pragma unroll
        for (int k = 0; k < 3; ++k) ai = dot4(xpk[k], wsi[WS_WIP + j * 3 + k], ai);
        res[j] = (float)ai * prod + wsf[WS_BQ + j];
    }
    float4* op = (float4*)(xw + (size_t)t * BH + b * HH);
#pragma unroll
    for (int k = 0; k < 5; ++k)
        op[k] = make_float4(res[4*k], res[4*k+1], res[4*k+2], res[4*k+3]);
}

// ---------------- kernel 4: serial recurrence, 1 workgroup -------------------
// 512 threads (8 waves, 2/SIMD), thread = one full batch row b. The six-round
// mystery (VGPR_Count pinned at 52-60 regardless of structure / launch bounds)
// was REMATERIALIZATION: wsi is const __restrict__, so the compiler legally
// re-loads the packed Wh from L2 every timestep instead of keeping it live.
// Fix: opaque `asm volatile("" : "+v"(whp[i]))` after the load — the value
// becomes an unknown asm result that CANNOT be rematerialized and must occupy
// a VGPR. amdgpu_waves_per_eu(2,2) -> 256-VGPR budget; live set ~190 fits.
// Per step: 100 reg-reg dot4 -> DPP wave max -> B1 -> waves 0-3: cross-wave
// reduce + scales + exact-tanhf LUT {level, bits(level*sh)}; tid0 posts
// {isa,sprod} -> B2 -> all: quantize + ds_read_b64 gather x20 (fused groups
// of 4: float4 store + hd dword pack). 2 LDS-only barriers, manual ping-pong.
__global__ __launch_bounds__(512)
__attribute__((amdgpu_waves_per_eu(2, 2)))
void k_rnn(const float* __restrict__ h0,
           const float* __restrict__ wsf,
           const int* __restrict__ wsi,
           float* __restrict__ xw) {
    __shared__ uint2 wred[8];
    __shared__ float bc2[2];
    __shared__ int2 lut[256];
    const int tid = threadIdx.x;
    const int b = tid;
    const float s_wh = wsf[WS_S_WH];
    float sprod = wsf[WS_S_H0] * s_wh;

    int whp[100];   // full packed Wh: rows j=0..19, 5 dwords each
#pragma unroll
    for (int i = 0; i < 100; ++i) whp[i] = wsi[WS_WHP + i];
#pragma unroll
    for (int i = 0; i < 100; ++i) asm volatile("" : "+v"(whp[i]));   // pin in VGPRs

    int hd[5];
    {   // h0 -> levels -> pack (whole row stays in this thread)
        float ish0 = wsf[WS_INV_SH0];
        const float4* hp = (const float4*)(h0 + b * HH);
        int lv[20];
#pragma unroll
        for (int k = 0; k < 5; ++k) {
            float4 v = hp[k];
            lv[4*k]   = qlevel(v.x, ish0);
            lv[4*k+1] = qlevel(v.y, ish0);
            lv[4*k+2] = qlevel(v.z, ish0);
            lv[4*k+3] = qlevel(v.w, ish0);
        }
#pragma unroll
        for (int k = 0; k < 5; ++k)
            hd[k] = pack4(lv[4*k], lv[4*k+1], lv[4*k+2], lv[4*k+3]);
    }

    float xw0[20], xw1[20];
    {   // preload row t=0
        const float4* p = (const float4*)(xw + b * HH);
#pragma unroll
        for (int k = 0; k < 5; ++k) {
            float4 v = p[k];
            xw0[4*k] = v.x; xw0[4*k+1] = v.y; xw0[4*k+2] = v.z; xw0[4*k+3] = v.w;
        }
    }
    const float4* pf = (const float4*)(xw + (size_t)BH + b * HH);  // row t+1
    float4*       po = (float4*)(xw + b * HH);                      // row t

    auto step = [&](int t, float (&xa)[20], float (&xb)[20]) {
        if (t + 1 < TT) {   // prefetch next row; stays in flight across barriers
#pragma unroll
            for (int k = 0; k < 5; ++k) {
                float4 v = pf[k];
                xb[4*k] = v.x; xb[4*k+1] = v.y; xb[4*k+2] = v.z; xb[4*k+3] = v.w;
            }
        }
        float acc[20];
#pragma unroll
        for (int j = 0; j < HH; ++j) {
            int ai = 0;
#pragma unroll
            for (int k = 0; k < 5; ++k) ai = dot4(hd[k], whp[j * 5 + k], ai);
            acc[j] = fmaf((float)ai, sprod, xa[j]);   // exact: |ai| < 2^24, pow2 scale
        }
        float mx = acc[0], mn = acc[0];
#pragma unroll
        for (int j = 1; j < HH; ++j) { mx = fmaxf(mx, acc[j]); mn = fminf(mn, acc[j]); }
        unsigned ea = wave_umax(fenc(mx));    // max(acc)
        unsigned eb = wave_umax(fenc(-mn));   // max(-acc)
        if ((tid & 63) == 63) wred[tid >> 6] = make_uint2(ea, eb);
        BAR();   // B1
        float isa;
        if (tid < 256) {   // waves 0-3 (one per SIMD): reduce + scales + LUT
            uint2 wp = wred[tid & 7];
            float ma = fdec(oct_umax(wp.x));
            float nm = fdec(oct_umax(wp.y));
            float sa; p2s(fmaxf(ma, nm), &sa, &isa);
            float lp = fmed3(rintf(ma * isa), -128.f, 127.f);
            float ln = fmed3(rintf(-nm * isa), -128.f, 127.f);
            float mlvl = fmaxf(fabsf(lp), fabsf(ln));   // max |acc_q| (clip asym incl.)
            float mh = tanhf(mlvl * sa);                // max |h_new| (tanh monotone)
            float sh, ish; p2s(mh, &sh, &ish);
            sprod = sh * s_wh;
            float tq = tanhf((float)(tid - 128) * sa);  // exact LUT entry
            int lv = (int)fmed3(rintf(tq * ish), -128.f, 127.f);
            lut[tid] = make_int2(lv, __float_as_int((float)lv * sh));
            if (tid == 0) { bc2[0] = isa; bc2[1] = sprod; }
        }
        BAR();   // B2
        if (tid >= 256) { isa = bc2[0]; sprod = bc2[1]; }
#pragma unroll
        for (int k = 0; k < 5; ++k) {   // fused epilogue, groups of 4
            int q0 = (int)fmed3(rintf(acc[4*k]   * isa), -128.f, 127.f);
            int q1 = (int)fmed3(rintf(acc[4*k+1] * isa), -128.f, 127.f);
            int q2 = (int)fmed3(rintf(acc[4*k+2] * isa), -128.f, 127.f);
            int q3 = (int)fmed3(rintf(acc[4*k+3] * isa), -128.f, 127.f);
            int2 e0 = lut[q0 + 128];
            int2 e1 = lut[q1 + 128];
            int2 e2 = lut[q2 + 128];
            int2 e3 = lut[q3 + 128];
            po[k] = make_float4(__int_as_float(e0.y), __int_as_float(e1.y),
                                __int_as_float(e2.y), __int_as_float(e3.y));
            hd[k] = pack4(e0.x, e1.x, e2.x, e3.x);
        }
        pf += BH / 4;
        po += BH / 4;
    };

    for (int t = 0; t < TT; t += 2) {   // ping-pong: no xa=xb copy
        step(t, xw0, xw1);
        step(t + 1, xw1, xw0);
    }
}

// ---------------- kernel 5: transpose [T][B][H] -> [B][T][H] -----------------
__global__ __launch_bounds__(256) void k_tr(const float* __restrict__ src, float* __restrict__ out) {
    __shared__ float tile[16 * 16 * HH];   // 20 KB
    int t0 = blockIdx.x * 16, b0 = blockIdx.y * 16;
    for (int i = threadIdx.x; i < 16 * 16 * HH; i += 256) {
        int r = i / (16 * HH), c = i % (16 * HH);
        tile[i] = src[(size_t)(t0 + r) * BH + b0 * HH + c];
    }
    __syncthreads();
    for (int i = threadIdx.x; i < 16 * 16 * HH; i += 256) {
        int bb = i / (16 * HH), rj = i % (16 * HH);
        int r = rj / HH, j = rj % HH;
        out[(size_t)(b0 + bb) * (TT * HH) + (t0 + r) * HH + j] = tile[r * (16 * HH) + bb * HH + j];
    }
}

extern "C" void kernel_launch(void* const* d_in, const int* in_sizes, int n_in,
                              void* d_out, int out_size, void* d_ws, size_t ws_size,
                              hipStream_t stream) {
    const float* x    = (const float*)d_in[0];
    const float* h0   = (const float*)d_in[1];
    const float* Wi   = (const float*)d_in[2];
    const float* Wh   = (const float*)d_in[3];
    const float* bias = (const float*)d_in[4];
    float* out = (float*)d_out;

    char* w = (char*)d_ws;
    float* wsf = (float*)w;
    int* wsi = (int*)w;
    unsigned* amax = (unsigned*)w;
    float* xw = (float*)(w + WS_XW_OFF);

    hipMemsetAsync(d_ws, 0, 64, stream);
    int n = in_sizes[0];
    k_amax<<<2048, 256, 0, stream>>>(x, n / 4, amax);
    k_prep<<<1, 256, 0, stream>>>(Wi, Wh, bias, h0, wsf, wsi);
    k_xw<<<(BB * TT) / 256, 256, 0, stream>>>(x, wsf, wsi, xw);
    k_rnn<<<1, 512, 0, stream>>>(h0, wsf, wsi, xw);
    k_tr<<<dim3(TT / 16, BB / 16), 256, 0, stream>>>(xw, out);
}

// Round 8
// 5294.272 us; speedup vs baseline: 1.1199x; 1.0221x over previous
//
#include <hip/hip_runtime.h>
#include <math.h>

// Problem constants: B=512, T=2048, D=10, H=20
#define BB 512
#define TT 2048
#define DD 10
#define HH 20
#define BH (BB*HH)          // 10240 elements per timestep

// ws layout (word indices from base)
#define WS_AMAX     0
#define WS_PROD_XWI 4
#define WS_INV_SX   5
#define WS_S_H0     6
#define WS_INV_SH0  7
#define WS_S_WH     8
#define WS_BQ       16
#define WS_WIP      40
#define WS_WHP      104
#define WS_XW_OFF   4096     // byte offset of xW / out_t buffer: [T][B][H] floats (84 MB)

// LDS-only barrier: never drains vmcnt (prefetch loads / output stores stay in flight)
#define BAR() asm volatile("s_waitcnt lgkmcnt(0)\n\ts_barrier" ::: "memory")

__device__ __forceinline__ int dot4(int a, int b, int c) {
    return __builtin_amdgcn_sdot4(a, b, c, false);
}

// scale = exp2(ceil(log2(max(m,1e-10))))/128 via exponent bits (exact, branchless)
__device__ __forceinline__ void p2s(float m, float* s, float* is) {
    m = fmaxf(m, 1e-10f);
    unsigned u = __float_as_uint(m);
    int k = (int)(u >> 23) - 127 + ((u & 0x7fffffu) ? 1 : 0);  // ceil(log2(m))
    *s  = __uint_as_float((unsigned)(k + 120) << 23);           // 2^(k-7)
    *is = __uint_as_float((unsigned)(134 - k) << 23);           // 2^(7-k)
}

__device__ __forceinline__ float fmed3(float a, float b, float c) {
    return __builtin_amdgcn_fmed3f(a, b, c);
}

__device__ __forceinline__ int qlevel(float v, float inv) {
    return (int)fmed3(rintf(v * inv), -128.f, 127.f);
}

__device__ __forceinline__ int pack4(int a, int b, int c, int d) {
    return (a & 255) | ((b & 255) << 8) | ((c & 255) << 16) | ((d & 255) << 24);
}

// monotone float<->uint encoding: order-preserving for all finite floats
__device__ __forceinline__ unsigned fenc(float x) {
    unsigned u = __float_as_uint(x);
    return u ^ (unsigned)(((int)u >> 31) | 0x80000000);
}
__device__ __forceinline__ float fdec(unsigned e) {
    unsigned mask = (~(unsigned)((int)e >> 31)) | 0x80000000u;
    return __uint_as_float(e ^ mask);
}

__device__ __forceinline__ unsigned umx(unsigned a, unsigned b) { return a > b ? a : b; }

// wave64 umax via DPP (VALU only, no LDS): lane63 holds the full max
__device__ __forceinline__ unsigned wave_umax(unsigned m) {
    unsigned t;
    t = (unsigned)__builtin_amdgcn_update_dpp(0, (int)m, 0x111, 0xf, 0xf, true); m = umx(m, t); // shr1
    t = (unsigned)__builtin_amdgcn_update_dpp(0, (int)m, 0x112, 0xf, 0xf, true); m = umx(m, t); // shr2
    t = (unsigned)__builtin_amdgcn_update_dpp(0, (int)m, 0x114, 0xf, 0xf, true); m = umx(m, t); // shr4
    t = (unsigned)__builtin_amdgcn_update_dpp(0, (int)m, 0x118, 0xf, 0xf, true); m = umx(m, t); // shr8
    t = (unsigned)__builtin_amdgcn_update_dpp(0, (int)m, 0x142, 0xa, 0xf, true); m = umx(m, t); // bcast15
    t = (unsigned)__builtin_amdgcn_update_dpp(0, (int)m, 0x143, 0xc, 0xf, true); m = umx(m, t); // bcast31
    return m;
}

// umax over each 16-lane row (cyclic): every lane gets the row max
__device__ __forceinline__ unsigned row_umax(unsigned m) {
    unsigned t;
    t = (unsigned)__builtin_amdgcn_update_dpp(0, (int)m, 0x121, 0xf, 0xf, true); m = umx(m, t); // ror1
    t = (unsigned)__builtin_amdgcn_update_dpp(0, (int)m, 0x122, 0xf, 0xf, true); m = umx(m, t); // ror2
    t = (unsigned)__builtin_amdgcn_update_dpp(0, (int)m, 0x124, 0xf, 0xf, true); m = umx(m, t); // ror4
    t = (unsigned)__builtin_amdgcn_update_dpp(0, (int)m, 0x128, 0xf, 0xf, true); m = umx(m, t); // ror8
    return m;
}

// pair (lanes 2k,2k+1) h-level merge: 3 quad_perm DPP + byte splices -> hd[5]
__device__ __forceinline__ void mk_hd(int PA, int PB, int PC, bool isLo, int* hd) {
    int QA = __builtin_amdgcn_update_dpp(0, PA, 0xB1, 0xf, 0xf, true); // quad_perm [1,0,3,2]
    int QB = __builtin_amdgcn_update_dpp(0, PB, 0xB1, 0xf, 0xf, true);
    int QC = __builtin_amdgcn_update_dpp(0, PC, 0xB1, 0xf, 0xf, true);
    int XA = isLo ? PA : QA, XB = isLo ? PB : QB, XC = isLo ? PC : QC;
    int YA = isLo ? QA : PA, YB = isLo ? QB : PB, YC = isLo ? QC : PC;
    hd[0] = XA; hd[1] = XB;
    hd[2] = (XC & 0xFFFF) | (YA << 16);
    hd[3] = (int)((unsigned)YA >> 16) | (YB << 16);
    hd[4] = (int)((unsigned)YB >> 16) | (YC << 16);
}

// ---------------- kernel 1: maxabs(x) grid reduction -------------------------
__global__ void k_amax(const float* __restrict__ x, int n4, unsigned* amax) {
    int g = blockIdx.x * blockDim.x + threadIdx.x;
    int stride = gridDim.x * blockDim.x;
    const float4* xv = (const float4*)x;
    float m = 0.f;
    for (int i = g; i < n4; i += stride) {
        float4 v = xv[i];
        m = fmaxf(m, fmaxf(fmaxf(fabsf(v.x), fabsf(v.y)), fmaxf(fabsf(v.z), fabsf(v.w))));
    }
#pragma unroll
    for (int off = 32; off; off >>= 1) m = fmaxf(m, __shfl_xor(m, off, 64));
    if ((threadIdx.x & 63) == 0) atomicMax(amax, __float_as_uint(m));
}

// ---------------- kernel 2: scales + weight quant/pack -----------------------
__device__ float bmaxabs(const float* p, int n, float* red, int tid) {
    float m = 0.f;
    for (int i = tid; i < n; i += 256) m = fmaxf(m, fabsf(p[i]));
    red[tid] = m; __syncthreads();
    for (int s = 128; s; s >>= 1) {
        if (tid < s) red[tid] = fmaxf(red[tid], red[tid + s]);
        __syncthreads();
    }
    m = red[0]; __syncthreads();
    return m;
}

__global__ void k_prep(const float* __restrict__ Wi, const float* __restrict__ Wh,
                       const float* __restrict__ bias, const float* __restrict__ h0,
                       float* wsf, int* wsi) {
    __shared__ float red[256];
    __shared__ float hdr[4];
    int tid = threadIdx.x;
    float mwi = bmaxabs(Wi, HH * DD, red, tid);
    float mwh = bmaxabs(Wh, HH * HH, red, tid);
    float mb  = bmaxabs(bias, HH, red, tid);
    float mh0 = bmaxabs(h0, BH, red, tid);
    if (tid == 0) {
        float mx = __uint_as_float(((unsigned*)wsf)[WS_AMAX]);
        float sx, isx, swi, iswi, swh, iswh, sb, isb, sh0, ish0;
        p2s(mx,  &sx,  &isx);
        p2s(mwi, &swi, &iswi);
        p2s(mwh, &swh, &iswh);
        p2s(mb,  &sb,  &isb);
        p2s(mh0, &sh0, &ish0);
        wsf[WS_PROD_XWI] = sx * swi;
        wsf[WS_INV_SX]   = isx;
        wsf[WS_S_H0]     = sh0;
        wsf[WS_INV_SH0]  = ish0;
        wsf[WS_S_WH]     = swh;
        hdr[0] = iswi; hdr[1] = iswh; hdr[2] = sb; hdr[3] = isb;
    }
    __syncthreads();
    if (tid < HH) {
        float iswi = hdr[0], iswh = hdr[1], sb = hdr[2], isb = hdr[3];
        int lv[20];
#pragma unroll
        for (int d = 0; d < DD; ++d) lv[d] = qlevel(Wi[tid * DD + d], iswi);
        lv[10] = 0; lv[11] = 0;
#pragma unroll
        for (int k = 0; k < 3; ++k)
            wsi[WS_WIP + tid * 3 + k] = pack4(lv[4*k], lv[4*k+1], lv[4*k+2], lv[4*k+3]);
#pragma unroll
        for (int k = 0; k < HH; ++k) lv[k] = qlevel(Wh[tid * HH + k], iswh);
#pragma unroll
        for (int k = 0; k < 5; ++k)
            wsi[WS_WHP + tid * 5 + k] = pack4(lv[4*k], lv[4*k+1], lv[4*k+2], lv[4*k+3]);
        wsf[WS_BQ + tid] = (float)qlevel(bias[tid], isb) * sb;
    }
}

// ---------------- kernel 3: xW[t][b][j] = quant(x)·Wi_q + bq -----------------
__global__ __launch_bounds__(256) void k_xw(const float* __restrict__ x,
                                            const float* __restrict__ wsf,
                                            const int* __restrict__ wsi,
                                            float* __restrict__ xw) {
    int g = blockIdx.x * 256 + threadIdx.x;
    int b = g & (BB - 1);
    int t = g >> 9;
    float isx  = wsf[WS_INV_SX];
    float prod = wsf[WS_PROD_XWI];
    const float2* xp = (const float2*)(x + ((size_t)b * TT + t) * DD);
    float xv[10];
#pragma unroll
    for (int k = 0; k < 5; ++k) { float2 v = xp[k]; xv[2*k] = v.x; xv[2*k+1] = v.y; }
    int lv[12];
#pragma unroll
    for (int d = 0; d < DD; ++d) lv[d] = qlevel(xv[d], isx);
    lv[10] = 0; lv[11] = 0;
    int xpk[3];
#pragma unroll
    for (int k = 0; k < 3; ++k) xpk[k] = pack4(lv[4*k], lv[4*k+1], lv[4*k+2], lv[4*k+3]);
    float res[20];
#pragma unroll
    for (int j = 0; j < HH; ++j) {
        int ai = 0;
#pragma unroll
        for (int k = 0; k < 3; ++k) ai = dot4(xpk[k], wsi[WS_WIP + j * 3 + k], ai);
        res[j] = (float)ai * prod + wsf[WS_BQ + j];
    }
    float4* op = (float4*)(xw + (size_t)t * BH + b * HH);
#pragma unroll
    for (int k = 0; k < 5; ++k)
        op[k] = make_float4(res[4*k], res[4*k+1], res[4*k+2], res[4*k+3]);
}

// ---------------- kernel 4: serial recurrence, 1 workgroup -------------------
// 1024 threads (16 waves = 4/SIMD), thread = (b, jhalf) with the PAIR IN THE
// SAME WAVE (b=tid>>1): h-exchange is 3 quad_perm DPPs, no extra barrier.
// whp[50] pinned into arch VGPRs via opaque asm (R7 proved the pin moves
// VGPR_Count; R7's full-row layout needed ~160 live > the 104 allocated, so
// the allocator bounced Wh through AGPRs — v_dot4 can't read AGPRs, costing
// ~50 v_accvgpr_read/step). Half-row live set ≈ 85-105 fits the 128-VGPR
// budget from amdgpu_waves_per_eu(4,4) -> no AGPR traffic, 4 waves/SIMD.
// Per step: 50 reg-reg dot4 -> DPP wave max -> B1 -> waves 0-3: cross-wave
// reduce + scales + exact-tanhf LUT {level, bits(level*sh)}; tid0 posts
// {isa,sprod} -> B2 -> all: quantize + ds_read_b64 gather -> float2 stores +
// DPP pair exchange. 2 LDS-only barriers, manual ping-pong.
__global__ __launch_bounds__(1024)
__attribute__((amdgpu_waves_per_eu(4, 4)))
void k_rnn(const float* __restrict__ h0,
           const float* __restrict__ wsf,
           const int* __restrict__ wsi,
           float* __restrict__ xw) {
    __shared__ uint2 wred[16];
    __shared__ float bc2[2];
    __shared__ int2 lut[256];
    const int tid = threadIdx.x;
    const int b = tid >> 1;
    const int jb = (tid & 1) * 10;
    const bool isLo = (tid & 1) == 0;
    const float s_wh = wsf[WS_S_WH];
    float sprod = wsf[WS_S_H0] * s_wh;

    int whp[50];   // 10 packed Wh rows (this thread's jhalf)
#pragma unroll
    for (int i = 0; i < 50; ++i) whp[i] = wsi[WS_WHP + jb * 5 + i];
#pragma unroll
    for (int i = 0; i < 50; ++i) asm volatile("" : "+v"(whp[i]));   // pin: no remat/AGPR

    int hd[5];
    {   // h0 -> levels -> pack -> pair exchange
        float ish0 = wsf[WS_INV_SH0];
        const float2* hp = (const float2*)(h0 + b * HH + jb);
        int lv[10];
#pragma unroll
        for (int k = 0; k < 5; ++k) {
            float2 v = hp[k];
            lv[2*k]   = qlevel(v.x, ish0);
            lv[2*k+1] = qlevel(v.y, ish0);
        }
        mk_hd(pack4(lv[0], lv[1], lv[2], lv[3]),
              pack4(lv[4], lv[5], lv[6], lv[7]),
              (lv[8] & 255) | ((lv[9] & 255) << 8), isLo, hd);
    }

    float xwA[10], xwB[10];
    {   // preload own half of row t=0
        const float2* p = (const float2*)(xw + b * HH + jb);
#pragma unroll
        for (int k = 0; k < 5; ++k) { float2 v = p[k]; xwA[2*k] = v.x; xwA[2*k+1] = v.y; }
    }
    const float2* pf = (const float2*)(xw + (size_t)BH + b * HH + jb);  // row t+1
    float2*       po = (float2*)(xw + b * HH + jb);                      // row t

    auto step = [&](int t, float (&xa)[10], float (&xb)[10]) {
        if (t + 1 < TT) {   // prefetch; stays in flight across LDS-only barriers
#pragma unroll
            for (int k = 0; k < 5; ++k) { float2 v = pf[k]; xb[2*k] = v.x; xb[2*k+1] = v.y; }
        }
        float acc[10];
#pragma unroll
        for (int jj = 0; jj < 10; ++jj) {
            int ai = 0;
#pragma unroll
            for (int k = 0; k < 5; ++k) ai = dot4(hd[k], whp[jj * 5 + k], ai);
            acc[jj] = fmaf((float)ai, sprod, xa[jj]);   // exact: |ai| < 2^24, pow2 scale
        }
        float mx = acc[0], mn = acc[0];
#pragma unroll
        for (int jj = 1; jj < 10; ++jj) { mx = fmaxf(mx, acc[jj]); mn = fminf(mn, acc[jj]); }
        unsigned ea = wave_umax(fenc(mx));    // max(acc)
        unsigned eb = wave_umax(fenc(-mn));   // max(-acc)
        if ((tid & 63) == 63) wred[tid >> 6] = make_uint2(ea, eb);
        BAR();   // B1
        float isa;
        if (tid < 256) {   // waves 0-3 (1/SIMD): cross-wave reduce + scales + LUT
            uint2 wp = wred[tid & 15];
            float ma = fdec(row_umax(wp.x));
            float nm = fdec(row_umax(wp.y));
            float sa; p2s(fmaxf(ma, nm), &sa, &isa);
            float lp = fmed3(rintf(ma * isa), -128.f, 127.f);
            float ln = fmed3(rintf(-nm * isa), -128.f, 127.f);
            float mlvl = fmaxf(fabsf(lp), fabsf(ln));   // max |acc_q| (clip asym incl.)
            float mh = tanhf(mlvl * sa);                // max |h_new| (tanh monotone)
            float sh, ish; p2s(mh, &sh, &ish);
            sprod = sh * s_wh;
            float tq = tanhf((float)(tid - 128) * sa);  // exact LUT entry
            int lv = (int)fmed3(rintf(tq * ish), -128.f, 127.f);
            lut[tid] = make_int2(lv, __float_as_int((float)lv * sh));
            if (tid == 0) { bc2[0] = isa; bc2[1] = sprod; }
        }
        BAR();   // B2
        if (tid >= 256) { isa = bc2[0]; sprod = bc2[1]; }
        int ql[10];
#pragma unroll
        for (int k = 0; k < 5; ++k) {   // fused epilogue: gather + store pairs
            int qa = (int)fmed3(rintf(acc[2*k]   * isa), -128.f, 127.f);
            int qb = (int)fmed3(rintf(acc[2*k+1] * isa), -128.f, 127.f);
            int2 e0 = lut[qa + 128];
            int2 e1 = lut[qb + 128];
            ql[2*k]   = e0.x;
            ql[2*k+1] = e1.x;
            po[k] = make_float2(__int_as_float(e0.y), __int_as_float(e1.y));
        }
        mk_hd(pack4(ql[0], ql[1], ql[2], ql[3]),
              pack4(ql[4], ql[5], ql[6], ql[7]),
              (ql[8] & 255) | ((ql[9] & 255) << 8), isLo, hd);
        pf += BH / 2;
        po += BH / 2;
    };

    for (int t = 0; t < TT; t += 2) {   // ping-pong: no xa=xb copy
        step(t, xwA, xwB);
        step(t + 1, xwB, xwA);
    }
}

// ---------------- kernel 5: transpose [T][B][H] -> [B][T][H] -----------------
__global__ __launch_bounds__(256) void k_tr(const float* __restrict__ src, float* __restrict__ out) {
    __shared__ float tile[16 * 16 * HH];   // 20 KB
    int t0 = blockIdx.x * 16, b0 = blockIdx.y * 16;
    for (int i = threadIdx.x; i < 16 * 16 * HH; i += 256) {
        int r = i / (16 * HH), c = i % (16 * HH);
        tile[i] = src[(size_t)(t0 + r) * BH + b0 * HH + c];
    }
    __syncthreads();
    for (int i = threadIdx.x; i < 16 * 16 * HH; i += 256) {
        int bb = i / (16 * HH), rj = i % (16 * HH);
        int r = rj / HH, j = rj % HH;
        out[(size_t)(b0 + bb) * (TT * HH) + (t0 + r) * HH + j] = tile[r * (16 * HH) + bb * HH + j];
    }
}

extern "C" void kernel_launch(void* const* d_in, const int* in_sizes, int n_in,
                              void* d_out, int out_size, void* d_ws, size_t ws_size,
                              hipStream_t stream) {
    const float* x    = (const float*)d_in[0];
    const float* h0   = (const float*)d_in[1];
    const float* Wi   = (const float*)d_in[2];
    const float* Wh   = (const float*)d_in[3];
    const float* bias = (const float*)d_in[4];
    float* out = (float*)d_out;

    char* w = (char*)d_ws;
    float* wsf = (float*)w;
    int* wsi = (int*)w;
    unsigned* amax = (unsigned*)w;
    float* xw = (float*)(w + WS_XW_OFF);

    hipMemsetAsync(d_ws, 0, 64, stream);
    int n = in_sizes[0];
    k_amax<<<2048, 256, 0, stream>>>(x, n / 4, amax);
    k_prep<<<1, 256, 0, stream>>>(Wi, Wh, bias, h0, wsf, wsi);
    k_xw<<<(BB * TT) / 256, 256, 0, stream>>>(x, wsf, wsi, xw);
    k_rnn<<<1, 1024, 0, stream>>>(h0, wsf, wsi, xw);
    k_tr<<<dim3(TT / 16, BB / 16), 256, 0, stream>>>(xw, out);
}